// Round 8
// baseline (3665.234 us; speedup 1.0000x reference)
//
#include <hip/hip_runtime.h>
#include <math.h>

#define TT  1024
#define DD  2048
#define NHH 2048
#define CC  1000

// ---------------------------------------------------------------------------
// Fused recurrent scan: the input-projection GEMM is folded into the scan's
// stall window — k_gemm is DELETED.
// Rationale (rounds 0-7): k_recur's round = 1.70us with only ~0.45us of
// issue (VALU 16%) -> ~1.2us idle stall per round waiting on cross-XCD
// visibility. The x-projections (xz[t]=x[t]@Wz[e]+bz, xh[t]=x[t]@Wh[e]) are
// fully independent of the recurrence and only needed one round later, so
// they are computed INSIDE the stall window, after the publish (critical
// path untouched). This removes the ~240us serial k_gemm entirely.
//  - per WG: 16 W rows (8 Wz + 8 Wh for its 8 owned elements) staged once
//    in LDS (128 KB; total LDS ~139 KB < 160, 1 WG/CU as before)
//  - per round (after publish): 4 dots/wave vs x[t] (read direct from
//    global, L3-resident broadcast row), butterfly, lane0 -> xp_s[2][16]
//    (double-buffered: round t writes (t+1)&1, reads t&1; races separated
//    by the existing mid/tail barriers)
//  - schedule/protocol otherwise EXACT r0/r6 (proven 1.70us): 4-slot tagged
//    u64 exchange, relaxed atomics, publish->validate slack = 1 round,
//    1 WG/CU x 256 thr (r2 lesson: per-CU path is sacred).
// ---------------------------------------------------------------------------
__global__ __launch_bounds__(256, 1) void k_recur(
    const float* __restrict__ X,
    const float* __restrict__ Wh, const float* __restrict__ Wz,
    const float* __restrict__ bz,
    const float* __restrict__ Uh, const float* __restrict__ Uz,
    const float* __restrict__ zt0, const float* __restrict__ ht0,
    const float* __restrict__ hp0,
    unsigned long long* __restrict__ Hbuf) {
    __shared__ float Wlds[16][DD];     // 128 KB: rows 0-7 Wz, 8-15 Wh
    __shared__ float Hs[NHH];
    __shared__ float dot_s[16];
    __shared__ float xp_s[2][16];
    const int tid  = threadIdx.x;
    const int wave = tid >> 6, lane = tid & 63;
    const int base8 = blockIdx.x * 8;

    // ---- U rows in registers (4 per wave: waves 0-1 Uz, 2-3 Uh) ----
    const float* __restrict__ Um = (wave < 2) ? Uz : Uh;
    const int r0 = base8 + (wave & 1) * 4;
    float u[4][32];
#pragma unroll
    for (int r = 0; r < 4; ++r) {
        const float* __restrict__ row = Um + (size_t)(r0 + r) * NHH;
#pragma unroll
        for (int c = 0; c < 8; ++c) {
            float4 v = *(const float4*)&row[c * 256 + lane * 4];
            u[r][c*4+0] = v.x; u[r][c*4+1] = v.y; u[r][c*4+2] = v.z; u[r][c*4+3] = v.w;
        }
    }

    // ---- stage this WG's 16 projection rows into LDS ----
#pragma unroll
    for (int j = 0; j < 8; ++j) {
        const float* __restrict__ rz = Wz + (size_t)(base8 + j) * DD;
        const float* __restrict__ rh = Wh + (size_t)(base8 + j) * DD;
        *(float4*)&Wlds[j][tid * 8]         = *(const float4*)&rz[tid * 8];
        *(float4*)&Wlds[j][tid * 8 + 4]     = *(const float4*)&rz[tid * 8 + 4];
        *(float4*)&Wlds[8 + j][tid * 8]     = *(const float4*)&rh[tid * 8];
        *(float4*)&Wlds[8 + j][tid * 8 + 4] = *(const float4*)&rh[tid * 8 + 4];
    }

    // ---- Hs = P_0 ; own P_1 ; publish epoch 1 ----
#pragma unroll
    for (int k = 0; k < 8; ++k) Hs[k * 256 + tid] = hp0[k * 256 + tid];
    float p_cur = 0.f, bz_r = 0.f;
    if (tid < 8) {
        float z0 = zt0[base8 + tid], g0 = ht0[base8 + tid], p0 = hp0[base8 + tid];
        p_cur = (1.0f - z0) * p0 + z0 * g0;
        bz_r = bz[base8 + tid];
        unsigned long long pr = (1ull << 32) | (unsigned long long)__float_as_uint(p_cur);
        __hip_atomic_store(&Hbuf[(size_t)1 * NHH + base8 + tid], pr,
                           __ATOMIC_RELAXED, __HIP_MEMORY_SCOPE_SYSTEM);
    }
    __syncthreads();   // Wlds + Hs ready

    // ---- prologue x-projection: row 0 -> xp_s[1] (read by round t=1) ----
    {
        const int j0 = ((wave >> 1) * 8) + (wave & 1) * 4;
        const float4* __restrict__ xrow = (const float4*)X;   // row 0
        float a0 = 0.f, a1 = 0.f, a2 = 0.f, a3 = 0.f;
#pragma unroll
        for (int c = 0; c < 8; ++c) {
            float4 xv = xrow[c * 64 + lane];
            float4 w0 = *(const float4*)&Wlds[j0 + 0][c * 256 + lane * 4];
            float4 w1 = *(const float4*)&Wlds[j0 + 1][c * 256 + lane * 4];
            float4 w2 = *(const float4*)&Wlds[j0 + 2][c * 256 + lane * 4];
            float4 w3 = *(const float4*)&Wlds[j0 + 3][c * 256 + lane * 4];
            a0 = fmaf(w0.x, xv.x, fmaf(w0.y, xv.y, fmaf(w0.z, xv.z, fmaf(w0.w, xv.w, a0))));
            a1 = fmaf(w1.x, xv.x, fmaf(w1.y, xv.y, fmaf(w1.z, xv.z, fmaf(w1.w, xv.w, a1))));
            a2 = fmaf(w2.x, xv.x, fmaf(w2.y, xv.y, fmaf(w2.z, xv.z, fmaf(w2.w, xv.w, a2))));
            a3 = fmaf(w3.x, xv.x, fmaf(w3.y, xv.y, fmaf(w3.z, xv.z, fmaf(w3.w, xv.w, a3))));
        }
#pragma unroll
        for (int off = 32; off > 0; off >>= 1) {
            a0 += __shfl_xor(a0, off); a1 += __shfl_xor(a1, off);
            a2 += __shfl_xor(a2, off); a3 += __shfl_xor(a3, off);
        }
        if (lane == 0) {
            int di = ((wave & 1) * 4) + ((wave >> 1) * 8);
            xp_s[1][di + 0] = a0; xp_s[1][di + 1] = a1;
            xp_s[1][di + 2] = a2; xp_s[1][di + 3] = a3;
        }
    }
    __syncthreads();   // xp_s[1] visible

    for (int t = 1; t < TT; ++t) {
        // (i) issue gather loads for epoch t; not touched until (iv)
        const unsigned long long* __restrict__ src = Hbuf + (size_t)(t & 3) * NHH;
        unsigned long long pv[8];
#pragma unroll
        for (int k = 0; k < 8; ++k)
            pv[k] = __hip_atomic_load(&src[k * 256 + tid], __ATOMIC_RELAXED, __HIP_MEMORY_SCOPE_SYSTEM);

        // (ii) matvec: U @ P_{t-1} from LDS, 4 rows/wave, U in registers
        float a0 = 0.f, a1 = 0.f, a2 = 0.f, a3 = 0.f;
#pragma unroll
        for (int c = 0; c < 8; ++c) {
            float4 h4 = *(const float4*)&Hs[c * 256 + lane * 4];
            a0 = fmaf(u[0][c*4+0], h4.x, fmaf(u[0][c*4+1], h4.y, fmaf(u[0][c*4+2], h4.z, fmaf(u[0][c*4+3], h4.w, a0))));
            a1 = fmaf(u[1][c*4+0], h4.x, fmaf(u[1][c*4+1], h4.y, fmaf(u[1][c*4+2], h4.z, fmaf(u[1][c*4+3], h4.w, a1))));
            a2 = fmaf(u[2][c*4+0], h4.x, fmaf(u[2][c*4+1], h4.y, fmaf(u[2][c*4+2], h4.z, fmaf(u[2][c*4+3], h4.w, a2))));
            a3 = fmaf(u[3][c*4+0], h4.x, fmaf(u[3][c*4+1], h4.y, fmaf(u[3][c*4+2], h4.z, fmaf(u[3][c*4+3], h4.w, a3))));
        }
#pragma unroll
        for (int off = 32; off > 0; off >>= 1) {
            a0 += __shfl_xor(a0, off); a1 += __shfl_xor(a1, off);
            a2 += __shfl_xor(a2, off); a3 += __shfl_xor(a3, off);
        }
        if (lane == 0) {
            int di = ((wave & 1) * 4) + ((wave >> 1) * 8); // Uz -> 0..7, Uh -> 8..15
            dot_s[di + 0] = a0; dot_s[di + 1] = a1; dot_s[di + 2] = a2; dot_s[di + 3] = a3;
        }
        __syncthreads();

        // (iii) gates from P_{t-1} dots + this round's x-proj; publish t+1
        if (tid < 8) {
            float z = 1.0f / (1.0f + expf(-(xp_s[t & 1][tid] + bz_r + dot_s[tid])));
            float g = tanhf(xp_s[t & 1][8 + tid] + dot_s[8 + tid]);
            float pn = (1.0f - z) * p_cur + z * g;
            p_cur = pn;
            unsigned long long pr = ((unsigned long long)(unsigned)(t + 1) << 32)
                                  | (unsigned long long)__float_as_uint(pn);
            __hip_atomic_store(&Hbuf[(size_t)((t + 1) & 3) * NHH + base8 + tid], pr,
                               __ATOMIC_RELAXED, __HIP_MEMORY_SCOPE_SYSTEM);
        }

        // (iii.5) x-projection for row t (used at round t+1) — stall filler.
        if (t < TT - 1) {
            const int j0 = ((wave >> 1) * 8) + (wave & 1) * 4;
            const float4* __restrict__ xrow = (const float4*)(X + (size_t)t * DD);
            float b0 = 0.f, b1 = 0.f, b2 = 0.f, b3 = 0.f;
#pragma unroll
            for (int c = 0; c < 8; ++c) {
                float4 xv = xrow[c * 64 + lane];
                float4 w0 = *(const float4*)&Wlds[j0 + 0][c * 256 + lane * 4];
                float4 w1 = *(const float4*)&Wlds[j0 + 1][c * 256 + lane * 4];
                float4 w2 = *(const float4*)&Wlds[j0 + 2][c * 256 + lane * 4];
                float4 w3 = *(const float4*)&Wlds[j0 + 3][c * 256 + lane * 4];
                b0 = fmaf(w0.x, xv.x, fmaf(w0.y, xv.y, fmaf(w0.z, xv.z, fmaf(w0.w, xv.w, b0))));
                b1 = fmaf(w1.x, xv.x, fmaf(w1.y, xv.y, fmaf(w1.z, xv.z, fmaf(w1.w, xv.w, b1))));
                b2 = fmaf(w2.x, xv.x, fmaf(w2.y, xv.y, fmaf(w2.z, xv.z, fmaf(w2.w, xv.w, b2))));
                b3 = fmaf(w3.x, xv.x, fmaf(w3.y, xv.y, fmaf(w3.z, xv.z, fmaf(w3.w, xv.w, b3))));
            }
#pragma unroll
            for (int off = 32; off > 0; off >>= 1) {
                b0 += __shfl_xor(b0, off); b1 += __shfl_xor(b1, off);
                b2 += __shfl_xor(b2, off); b3 += __shfl_xor(b3, off);
            }
            if (lane == 0) {
                int di = ((wave & 1) * 4) + ((wave >> 1) * 8);
                xp_s[(t + 1) & 1][di + 0] = b0; xp_s[(t + 1) & 1][di + 1] = b1;
                xp_s[(t + 1) & 1][di + 2] = b2; xp_s[(t + 1) & 1][di + 3] = b3;
            }
        }

        // (iv) validate epoch-t tags; batched parallel retry of stale ones
        for (;;) {
            unsigned stale = 0;
#pragma unroll
            for (int k = 0; k < 8; ++k)
                if ((unsigned)(pv[k] >> 32) != (unsigned)t) stale |= (1u << k);
            if (!stale) break;
#pragma unroll
            for (int k = 0; k < 8; ++k)
                if (stale & (1u << k))
                    pv[k] = __hip_atomic_load(&src[k * 256 + tid], __ATOMIC_RELAXED, __HIP_MEMORY_SCOPE_SYSTEM);
        }
#pragma unroll
        for (int k = 0; k < 8; ++k) Hs[k * 256 + tid] = __uint_as_float((unsigned)pv[k]);
        __syncthreads();
    }
}

// ---------------------------------------------------------------------------
// logits[r] = Wout[r,:] . P_1024   (epoch 1024 -> slot 0, value in low bits)
// ---------------------------------------------------------------------------
__global__ __launch_bounds__(256) void k_logits(const unsigned long long* __restrict__ Hbuf,
                                                const float* __restrict__ Wout,
                                                float* __restrict__ lg) {
    __shared__ float Hs[NHH];
    const int tid = threadIdx.x;
    for (int k = tid; k < NHH; k += 256) Hs[k] = __uint_as_float((unsigned)Hbuf[k]);
    __syncthreads();
    const int wave = tid >> 6, lane = tid & 63;
    const int row = blockIdx.x * 4 + wave;
    float a = 0.f;
#pragma unroll
    for (int c = 0; c < 8; ++c) {
        float4 w = *(const float4*)&Wout[(size_t)row * NHH + c * 256 + lane * 4];
        float4 h = *(const float4*)&Hs[c * 256 + lane * 4];
        a = fmaf(w.x, h.x, fmaf(w.y, h.y, fmaf(w.z, h.z, fmaf(w.w, h.w, a))));
    }
#pragma unroll
    for (int off = 32; off > 0; off >>= 1) a += __shfl_xor(a, off);
    if (lane == 0) lg[row] = a;
}

// ---------------------------------------------------------------------------
// softmax over 1000 logits, single block
// ---------------------------------------------------------------------------
__global__ __launch_bounds__(1024) void k_softmax(const float* __restrict__ lg,
                                                  float* __restrict__ out) {
    const int i = threadIdx.x;
    __shared__ float red[16];
    __shared__ float bc[2];
    float v = (i < CC) ? lg[i] : -3.0e38f;
    float m = v;
#pragma unroll
    for (int off = 32; off > 0; off >>= 1) m = fmaxf(m, __shfl_xor(m, off));
    if ((i & 63) == 0) red[i >> 6] = m;
    __syncthreads();
    if (i == 0) { float mm = red[0]; for (int k = 1; k < 16; ++k) mm = fmaxf(mm, red[k]); bc[0] = mm; }
    __syncthreads();
    float e = (i < CC) ? expf(v - bc[0]) : 0.f;
    float s = e;
#pragma unroll
    for (int off = 32; off > 0; off >>= 1) s += __shfl_xor(s, off);
    if ((i & 63) == 0) red[i >> 6] = s;
    __syncthreads();
    if (i == 0) { float ss = 0.f; for (int k = 0; k < 16; ++k) ss += red[k]; bc[1] = ss; }
    __syncthreads();
    if (i < CC) out[i] = e / bc[1];
}

extern "C" void kernel_launch(void* const* d_in, const int* in_sizes, int n_in,
                              void* d_out, int out_size, void* d_ws, size_t ws_size,
                              hipStream_t stream) {
    const float* x    = (const float*)d_in[0];
    const float* Wh   = (const float*)d_in[1];
    const float* Wz   = (const float*)d_in[2];
    // d_in[3] = Wr  (dead code in reference)
    const float* Uh   = (const float*)d_in[4];
    const float* Uz   = (const float*)d_in[5];
    const float* bz   = (const float*)d_in[6];
    // d_in[7] = Ur, d_in[8] = br (dead code)
    const float* Wout = (const float*)d_in[9];
    // d_in[10] = h0 (overwritten before first use since T>=1)
    const float* zt0  = (const float*)d_in[11];
    const float* ht0  = (const float*)d_in[12];
    const float* hp0  = (const float*)d_in[13];
    float* out = (float*)d_out;

    unsigned long long* Hbuf = (unsigned long long*)d_ws;       // 4*NH u64
    float* lg = (float*)(Hbuf + 4 * NHH);                       // CC f32

    k_recur<<<dim3(256), dim3(256), 0, stream>>>(x, Wh, Wz, bz, Uh, Uz, zt0, ht0, hp0, Hbuf);
    k_logits<<<dim3(250), dim3(256), 0, stream>>>(Hbuf, Wout, lg);
    k_softmax<<<dim3(1), dim3(1024), 0, stream>>>(lg, out);
}

// Round 9
// 2579.429 us; speedup vs baseline: 1.4209x; 1.4209x over previous
//
#include <hip/hip_runtime.h>
#include <math.h>

#define TT  1024
#define DD  2048
#define NHH 2048
#define CC  1000
#define WPAD 2052   // Wlds row stride: rows staggered 4 banks apart

// ---------------------------------------------------------------------------
// Fused recurrent scan (k_gemm deleted). Round-8 lesson: the fused x-proj
// MUST be pinned after the publish — the compiler otherwise schedules its
// cold x-row vmcnt + LDS reads into the validate->publish critical path
// (C_pub), inflating R = C_pub + L_vis from 1.7 to 3.6us. Fixes here:
//  1. sched_barrier(0) right after the publish store: nothing from the
//     x-proj region can move before it -> C_pub back to ~0.5us.
//  2. x row t prefetched into REGISTERS at phase (i) (issued with the
//     epoch gathers, consumed at (iii.5)) -> HBM latency covered by matvec.
//  3. Wlds rows padded to 2052 floats (row j starts at bank 4j%32) ->
//     kills the 2^18 cross-wave same-bank conflicts of r8.
// Everything else EXACT r0/r6 proven schedule (1.70us/round): 4-slot tagged
// u64 exchange, relaxed atomics, publish->validate slack = 1 round,
// 256 WGs x 256 thr (1 WG/CU), U rows in registers, dot_s reduce.
// ---------------------------------------------------------------------------
__global__ __launch_bounds__(256, 1) void k_recur(
    const float* __restrict__ X,
    const float* __restrict__ Wh, const float* __restrict__ Wz,
    const float* __restrict__ bz,
    const float* __restrict__ Uh, const float* __restrict__ Uz,
    const float* __restrict__ zt0, const float* __restrict__ ht0,
    const float* __restrict__ hp0,
    unsigned long long* __restrict__ Hbuf) {
    __shared__ float Wlds[16 * WPAD];   // rows 0-7 Wz, 8-15 Wh (padded stride)
    __shared__ float Hs[NHH];
    __shared__ float dot_s[16];
    __shared__ float xp_s[2][16];
    const int tid  = threadIdx.x;
    const int wave = tid >> 6, lane = tid & 63;
    const int base8 = blockIdx.x * 8;

    // ---- U rows in registers (4 per wave: waves 0-1 Uz, 2-3 Uh) ----
    const float* __restrict__ Um = (wave < 2) ? Uz : Uh;
    const int r0 = base8 + (wave & 1) * 4;
    float u[4][32];
#pragma unroll
    for (int r = 0; r < 4; ++r) {
        const float* __restrict__ row = Um + (size_t)(r0 + r) * NHH;
#pragma unroll
        for (int c = 0; c < 8; ++c) {
            float4 v = *(const float4*)&row[c * 256 + lane * 4];
            u[r][c*4+0] = v.x; u[r][c*4+1] = v.y; u[r][c*4+2] = v.z; u[r][c*4+3] = v.w;
        }
    }

    // ---- stage this WG's 16 projection rows into LDS (padded rows) ----
#pragma unroll
    for (int j = 0; j < 8; ++j) {
        const float* __restrict__ rz = Wz + (size_t)(base8 + j) * DD;
        const float* __restrict__ rh = Wh + (size_t)(base8 + j) * DD;
        *(float4*)&Wlds[j * WPAD + tid * 8]           = *(const float4*)&rz[tid * 8];
        *(float4*)&Wlds[j * WPAD + tid * 8 + 4]       = *(const float4*)&rz[tid * 8 + 4];
        *(float4*)&Wlds[(8 + j) * WPAD + tid * 8]     = *(const float4*)&rh[tid * 8];
        *(float4*)&Wlds[(8 + j) * WPAD + tid * 8 + 4] = *(const float4*)&rh[tid * 8 + 4];
    }

    // ---- Hs = P_0 ; own P_1 ; publish epoch 1 ----
#pragma unroll
    for (int k = 0; k < 8; ++k) Hs[k * 256 + tid] = hp0[k * 256 + tid];
    float p_cur = 0.f, bz_r = 0.f;
    if (tid < 8) {
        float z0 = zt0[base8 + tid], g0 = ht0[base8 + tid], p0 = hp0[base8 + tid];
        p_cur = (1.0f - z0) * p0 + z0 * g0;
        bz_r = bz[base8 + tid];
        unsigned long long pr = (1ull << 32) | (unsigned long long)__float_as_uint(p_cur);
        __hip_atomic_store(&Hbuf[(size_t)1 * NHH + base8 + tid], pr,
                           __ATOMIC_RELAXED, __HIP_MEMORY_SCOPE_SYSTEM);
    }
    __syncthreads();   // Wlds + Hs ready

    const int j0 = ((wave >> 1) * 8) + (wave & 1) * 4;   // this wave's 4 W rows
    // ---- prologue x-projection: row 0 -> xp_s[1] (read by round t=1) ----
    {
        const float4* __restrict__ xrow = (const float4*)X;   // row 0
        float a0 = 0.f, a1 = 0.f, a2 = 0.f, a3 = 0.f;
#pragma unroll
        for (int c = 0; c < 8; ++c) {
            float4 xv = xrow[c * 64 + lane];
            float4 w0 = *(const float4*)&Wlds[(j0 + 0) * WPAD + c * 256 + lane * 4];
            float4 w1 = *(const float4*)&Wlds[(j0 + 1) * WPAD + c * 256 + lane * 4];
            float4 w2 = *(const float4*)&Wlds[(j0 + 2) * WPAD + c * 256 + lane * 4];
            float4 w3 = *(const float4*)&Wlds[(j0 + 3) * WPAD + c * 256 + lane * 4];
            a0 = fmaf(w0.x, xv.x, fmaf(w0.y, xv.y, fmaf(w0.z, xv.z, fmaf(w0.w, xv.w, a0))));
            a1 = fmaf(w1.x, xv.x, fmaf(w1.y, xv.y, fmaf(w1.z, xv.z, fmaf(w1.w, xv.w, a1))));
            a2 = fmaf(w2.x, xv.x, fmaf(w2.y, xv.y, fmaf(w2.z, xv.z, fmaf(w2.w, xv.w, a2))));
            a3 = fmaf(w3.x, xv.x, fmaf(w3.y, xv.y, fmaf(w3.z, xv.z, fmaf(w3.w, xv.w, a3))));
        }
#pragma unroll
        for (int off = 32; off > 0; off >>= 1) {
            a0 += __shfl_xor(a0, off); a1 += __shfl_xor(a1, off);
            a2 += __shfl_xor(a2, off); a3 += __shfl_xor(a3, off);
        }
        if (lane == 0) {
            int di = ((wave & 1) * 4) + ((wave >> 1) * 8);
            xp_s[1][di + 0] = a0; xp_s[1][di + 1] = a1;
            xp_s[1][di + 2] = a2; xp_s[1][di + 3] = a3;
        }
    }
    __syncthreads();   // xp_s[1] visible

    for (int t = 1; t < TT; ++t) {
        // (i) issue epoch-t gather loads AND prefetch x row t into registers
        const unsigned long long* __restrict__ src = Hbuf + (size_t)(t & 3) * NHH;
        unsigned long long pv[8];
#pragma unroll
        for (int k = 0; k < 8; ++k)
            pv[k] = __hip_atomic_load(&src[k * 256 + tid], __ATOMIC_RELAXED, __HIP_MEMORY_SCOPE_SYSTEM);
        float4 xr[8];
        if (t < TT - 1) {
            const float4* __restrict__ xrow = (const float4*)(X + (size_t)t * DD);
#pragma unroll
            for (int c = 0; c < 8; ++c) xr[c] = xrow[c * 64 + lane];
        }

        // (ii) matvec: U @ P_{t-1} from LDS, 4 rows/wave, U in registers
        float a0 = 0.f, a1 = 0.f, a2 = 0.f, a3 = 0.f;
#pragma unroll
        for (int c = 0; c < 8; ++c) {
            float4 h4 = *(const float4*)&Hs[c * 256 + lane * 4];
            a0 = fmaf(u[0][c*4+0], h4.x, fmaf(u[0][c*4+1], h4.y, fmaf(u[0][c*4+2], h4.z, fmaf(u[0][c*4+3], h4.w, a0))));
            a1 = fmaf(u[1][c*4+0], h4.x, fmaf(u[1][c*4+1], h4.y, fmaf(u[1][c*4+2], h4.z, fmaf(u[1][c*4+3], h4.w, a1))));
            a2 = fmaf(u[2][c*4+0], h4.x, fmaf(u[2][c*4+1], h4.y, fmaf(u[2][c*4+2], h4.z, fmaf(u[2][c*4+3], h4.w, a2))));
            a3 = fmaf(u[3][c*4+0], h4.x, fmaf(u[3][c*4+1], h4.y, fmaf(u[3][c*4+2], h4.z, fmaf(u[3][c*4+3], h4.w, a3))));
        }
#pragma unroll
        for (int off = 32; off > 0; off >>= 1) {
            a0 += __shfl_xor(a0, off); a1 += __shfl_xor(a1, off);
            a2 += __shfl_xor(a2, off); a3 += __shfl_xor(a3, off);
        }
        if (lane == 0) {
            int di = ((wave & 1) * 4) + ((wave >> 1) * 8); // Uz -> 0..7, Uh -> 8..15
            dot_s[di + 0] = a0; dot_s[di + 1] = a1; dot_s[di + 2] = a2; dot_s[di + 3] = a3;
        }
        __syncthreads();

        // (iii) gates + publish epoch t+1 — the critical publish path.
        if (tid < 8) {
            float z = 1.0f / (1.0f + expf(-(xp_s[t & 1][tid] + bz_r + dot_s[tid])));
            float g = tanhf(xp_s[t & 1][8 + tid] + dot_s[8 + tid]);
            float pn = (1.0f - z) * p_cur + z * g;
            p_cur = pn;
            unsigned long long pr = ((unsigned long long)(unsigned)(t + 1) << 32)
                                  | (unsigned long long)__float_as_uint(pn);
            __hip_atomic_store(&Hbuf[(size_t)((t + 1) & 3) * NHH + base8 + tid], pr,
                               __ATOMIC_RELAXED, __HIP_MEMORY_SCOPE_SYSTEM);
        }
        // pin: NOTHING below may be scheduled before the publish store.
        __builtin_amdgcn_sched_barrier(0);

        // (iii.5) x-projection for row t (used at round t+1) — stall filler,
        // x already in registers, W in padded LDS.
        if (t < TT - 1) {
            float b0 = 0.f, b1 = 0.f, b2 = 0.f, b3 = 0.f;
#pragma unroll
            for (int c = 0; c < 8; ++c) {
                float4 xv = xr[c];
                float4 w0 = *(const float4*)&Wlds[(j0 + 0) * WPAD + c * 256 + lane * 4];
                float4 w1 = *(const float4*)&Wlds[(j0 + 1) * WPAD + c * 256 + lane * 4];
                float4 w2 = *(const float4*)&Wlds[(j0 + 2) * WPAD + c * 256 + lane * 4];
                float4 w3 = *(const float4*)&Wlds[(j0 + 3) * WPAD + c * 256 + lane * 4];
                b0 = fmaf(w0.x, xv.x, fmaf(w0.y, xv.y, fmaf(w0.z, xv.z, fmaf(w0.w, xv.w, b0))));
                b1 = fmaf(w1.x, xv.x, fmaf(w1.y, xv.y, fmaf(w1.z, xv.z, fmaf(w1.w, xv.w, b1))));
                b2 = fmaf(w2.x, xv.x, fmaf(w2.y, xv.y, fmaf(w2.z, xv.z, fmaf(w2.w, xv.w, b2))));
                b3 = fmaf(w3.x, xv.x, fmaf(w3.y, xv.y, fmaf(w3.z, xv.z, fmaf(w3.w, xv.w, b3))));
            }
#pragma unroll
            for (int off = 32; off > 0; off >>= 1) {
                b0 += __shfl_xor(b0, off); b1 += __shfl_xor(b1, off);
                b2 += __shfl_xor(b2, off); b3 += __shfl_xor(b3, off);
            }
            if (lane == 0) {
                int di = ((wave & 1) * 4) + ((wave >> 1) * 8);
                xp_s[(t + 1) & 1][di + 0] = b0; xp_s[(t + 1) & 1][di + 1] = b1;
                xp_s[(t + 1) & 1][di + 2] = b2; xp_s[(t + 1) & 1][di + 3] = b3;
            }
        }

        // (iv) validate epoch-t tags; batched parallel retry of stale ones
        for (;;) {
            unsigned stale = 0;
#pragma unroll
            for (int k = 0; k < 8; ++k)
                if ((unsigned)(pv[k] >> 32) != (unsigned)t) stale |= (1u << k);
            if (!stale) break;
#pragma unroll
            for (int k = 0; k < 8; ++k)
                if (stale & (1u << k))
                    pv[k] = __hip_atomic_load(&src[k * 256 + tid], __ATOMIC_RELAXED, __HIP_MEMORY_SCOPE_SYSTEM);
        }
#pragma unroll
        for (int k = 0; k < 8; ++k) Hs[k * 256 + tid] = __uint_as_float((unsigned)pv[k]);
        __syncthreads();
    }
}

// ---------------------------------------------------------------------------
// logits[r] = Wout[r,:] . P_1024   (epoch 1024 -> slot 0, value in low bits)
// ---------------------------------------------------------------------------
__global__ __launch_bounds__(256) void k_logits(const unsigned long long* __restrict__ Hbuf,
                                                const float* __restrict__ Wout,
                                                float* __restrict__ lg) {
    __shared__ float Hs[NHH];
    const int tid = threadIdx.x;
    for (int k = tid; k < NHH; k += 256) Hs[k] = __uint_as_float((unsigned)Hbuf[k]);
    __syncthreads();
    const int wave = tid >> 6, lane = tid & 63;
    const int row = blockIdx.x * 4 + wave;
    float a = 0.f;
#pragma unroll
    for (int c = 0; c < 8; ++c) {
        float4 w = *(const float4*)&Wout[(size_t)row * NHH + c * 256 + lane * 4];
        float4 h = *(const float4*)&Hs[c * 256 + lane * 4];
        a = fmaf(w.x, h.x, fmaf(w.y, h.y, fmaf(w.z, h.z, fmaf(w.w, h.w, a))));
    }
#pragma unroll
    for (int off = 32; off > 0; off >>= 1) a += __shfl_xor(a, off);
    if (lane == 0) lg[row] = a;
}

// ---------------------------------------------------------------------------
// softmax over 1000 logits, single block
// ---------------------------------------------------------------------------
__global__ __launch_bounds__(1024) void k_softmax(const float* __restrict__ lg,
                                                  float* __restrict__ out) {
    const int i = threadIdx.x;
    __shared__ float red[16];
    __shared__ float bc[2];
    float v = (i < CC) ? lg[i] : -3.0e38f;
    float m = v;
#pragma unroll
    for (int off = 32; off > 0; off >>= 1) m = fmaxf(m, __shfl_xor(m, off));
    if ((i & 63) == 0) red[i >> 6] = m;
    __syncthreads();
    if (i == 0) { float mm = red[0]; for (int k = 1; k < 16; ++k) mm = fmaxf(mm, red[k]); bc[0] = mm; }
    __syncthreads();
    float e = (i < CC) ? expf(v - bc[0]) : 0.f;
    float s = e;
#pragma unroll
    for (int off = 32; off > 0; off >>= 1) s += __shfl_xor(s, off);
    if ((i & 63) == 0) red[i >> 6] = s;
    __syncthreads();
    if (i == 0) { float ss = 0.f; for (int k = 0; k < 16; ++k) ss += red[k]; bc[1] = ss; }
    __syncthreads();
    if (i < CC) out[i] = e / bc[1];
}

extern "C" void kernel_launch(void* const* d_in, const int* in_sizes, int n_in,
                              void* d_out, int out_size, void* d_ws, size_t ws_size,
                              hipStream_t stream) {
    const float* x    = (const float*)d_in[0];
    const float* Wh   = (const float*)d_in[1];
    const float* Wz   = (const float*)d_in[2];
    // d_in[3] = Wr  (dead code in reference)
    const float* Uh   = (const float*)d_in[4];
    const float* Uz   = (const float*)d_in[5];
    const float* bz   = (const float*)d_in[6];
    // d_in[7] = Ur, d_in[8] = br (dead code)
    const float* Wout = (const float*)d_in[9];
    // d_in[10] = h0 (overwritten before first use since T>=1)
    const float* zt0  = (const float*)d_in[11];
    const float* ht0  = (const float*)d_in[12];
    const float* hp0  = (const float*)d_in[13];
    float* out = (float*)d_out;

    unsigned long long* Hbuf = (unsigned long long*)d_ws;       // 4*NH u64
    float* lg = (float*)(Hbuf + 4 * NHH);                       // CC f32

    k_recur<<<dim3(256), dim3(256), 0, stream>>>(x, Wh, Wz, bz, Uh, Uz, zt0, ht0, hp0, Hbuf);
    k_logits<<<dim3(250), dim3(256), 0, stream>>>(Hbuf, Wout, lg);
    k_softmax<<<dim3(1), dim3(1024), 0, stream>>>(lg, out);
}

// Round 10
// 2031.432 us; speedup vs baseline: 1.8043x; 1.2698x over previous
//
#include <hip/hip_runtime.h>
#include <math.h>

#define TT  1024
#define DD  2048
#define NHH 2048
#define CC  1000

// ---------------------------------------------------------------------------
// GEMM: XH = x @ Wh^T ; XZ = x @ Wz^T + bz   (fp32)
// 128x128 tile, BK=32, 256 threads, 8x8 micro-tile, register-prefetch dbuf.
// grid (NHH/128, TT/128, 2) = 256 blocks = exactly 1/CU.
// r7 measurement: GEMM time is insensitive to tile shape (64^2 vs 128^2
// within 3us) — near its fp32-issue envelope at these shapes.
// ---------------------------------------------------------------------------
__global__ __launch_bounds__(256) void k_gemm(const float* __restrict__ X,
                                              const float* __restrict__ Wh,
                                              const float* __restrict__ Wz,
                                              const float* __restrict__ bz,
                                              float* __restrict__ XH,
                                              float* __restrict__ XZ) {
    __shared__ float As[32][132];   // [k][m], +4 pad
    __shared__ float Bs[32][132];   // [k][n]
    const int z = blockIdx.z;
    const float* __restrict__ W = z ? Wz : Wh;
    float* __restrict__ OUT = z ? XZ : XH;
    const int n0 = blockIdx.x * 128;
    const int m0 = blockIdx.y * 128;
    const int tid = threadIdx.x;
    const int tx = tid & 15, ty = tid >> 4;   // 16x16 thread grid, 8x8 micro
    const int lr = tid >> 1;                  // staging row 0..127
    const int lq = (tid & 1) * 16;            // staging col base 0 / 16

    float4 pa[4], pb[4];
#pragma unroll
    for (int q = 0; q < 4; ++q) {             // prologue: tile 0 -> regs
        pa[q] = *(const float4*)&X[(size_t)(m0 + lr) * DD + lq + q * 4];
        pb[q] = *(const float4*)&W[(size_t)(n0 + lr) * DD + lq + q * 4];
    }
    float acc[8][8] = {};
    for (int k0 = 0; k0 < DD; k0 += 32) {
        // staged regs -> LDS (transposed to [k][m])
#pragma unroll
        for (int q = 0; q < 4; ++q) {
            const int kc = lq + q * 4;
            As[kc+0][lr]=pa[q].x; As[kc+1][lr]=pa[q].y; As[kc+2][lr]=pa[q].z; As[kc+3][lr]=pa[q].w;
            Bs[kc+0][lr]=pb[q].x; Bs[kc+1][lr]=pb[q].y; Bs[kc+2][lr]=pb[q].z; Bs[kc+3][lr]=pb[q].w;
        }
        __syncthreads();
        if (k0 + 32 < DD) {                   // prefetch next tile into regs
#pragma unroll
            for (int q = 0; q < 4; ++q) {
                pa[q] = *(const float4*)&X[(size_t)(m0 + lr) * DD + k0 + 32 + lq + q * 4];
                pb[q] = *(const float4*)&W[(size_t)(n0 + lr) * DD + k0 + 32 + lq + q * 4];
            }
        }
#pragma unroll
        for (int kk = 0; kk < 32; ++kk) {
            float4 a0 = *(const float4*)&As[kk][ty * 8];
            float4 a1 = *(const float4*)&As[kk][ty * 8 + 4];
            float4 b0 = *(const float4*)&Bs[kk][tx * 8];
            float4 b1 = *(const float4*)&Bs[kk][tx * 8 + 4];
            float a[8] = {a0.x,a0.y,a0.z,a0.w,a1.x,a1.y,a1.z,a1.w};
            float b[8] = {b0.x,b0.y,b0.z,b0.w,b1.x,b1.y,b1.z,b1.w};
#pragma unroll
            for (int i = 0; i < 8; ++i)
#pragma unroll
                for (int j = 0; j < 8; ++j)
                    acc[i][j] = fmaf(a[i], b[j], acc[i][j]);
        }
        __syncthreads();
    }
    float4 bias0 = make_float4(0.f,0.f,0.f,0.f), bias1 = bias0;
    if (z) {
        bias0 = *(const float4*)&bz[n0 + tx * 8];
        bias1 = *(const float4*)&bz[n0 + tx * 8 + 4];
    }
#pragma unroll
    for (int i = 0; i < 8; ++i) {
        float4 o0 = make_float4(acc[i][0]+bias0.x, acc[i][1]+bias0.y,
                                acc[i][2]+bias0.z, acc[i][3]+bias0.w);
        float4 o1 = make_float4(acc[i][4]+bias1.x, acc[i][5]+bias1.y,
                                acc[i][6]+bias1.z, acc[i][7]+bias1.w);
        *(float4*)&OUT[(size_t)(m0 + ty * 8 + i) * NHH + n0 + tx * 8] = o0;
        *(float4*)&OUT[(size_t)(m0 + ty * 8 + i) * NHH + n0 + tx * 8 + 4] = o1;
    }
}

// ---------------------------------------------------------------------------
// Recurrent scan — the proven 1.70us/round schedule (r0/r6/r7).
// Session conclusion: LATENCY ROOFLINE. 1023 serial all-to-all chip-wide
// exchanges; round = {matvec ∥ gather -> reduce -> barrier -> gates ->
// publish -> validate -> Hs -> barrier} + cross-XCD visibility + 256-WG
// straggler skew. HBM 1%, VALU 16%, 0 conflicts, occupancy irrelevant.
// Refuted levers: 2-step rounds (r1), fewer/larger WGs (r2), system-scope
// store (r3), single-writer lines (r4), span-2 validate (r5), scope matrix
// (r6 ≡), fused input GEMM (r8/r9 — stall window is not free).
// ---------------------------------------------------------------------------
__global__ __launch_bounds__(256, 1) void k_recur(
    const float* __restrict__ XH, const float* __restrict__ XZ,
    const float* __restrict__ Uh, const float* __restrict__ Uz,
    const float* __restrict__ zt0, const float* __restrict__ ht0,
    const float* __restrict__ hp0,
    unsigned long long* __restrict__ Hbuf) {
    __shared__ float Hs[NHH];
    __shared__ float dot_s[16];
    const int tid  = threadIdx.x;
    const int wave = tid >> 6, lane = tid & 63;
    const int base8 = blockIdx.x * 8;

    // load this wave's 4 U rows into registers
    const float* __restrict__ Um = (wave < 2) ? Uz : Uh;
    const int r0 = base8 + (wave & 1) * 4;
    float u[4][32];
#pragma unroll
    for (int r = 0; r < 4; ++r) {
        const float* __restrict__ row = Um + (size_t)(r0 + r) * NHH;
#pragma unroll
        for (int c = 0; c < 8; ++c) {
            float4 v = *(const float4*)&row[c * 256 + lane * 4];
            u[r][c*4+0] = v.x; u[r][c*4+1] = v.y; u[r][c*4+2] = v.z; u[r][c*4+3] = v.w;
        }
    }
    // Hs = P_0 = hprev0 (plain input, no tags needed for epoch 0)
#pragma unroll
    for (int k = 0; k < 8; ++k) Hs[k * 256 + tid] = hp0[k * 256 + tid];

    // own P_1 from initial gates; publish epoch 1
    float p_cur = 0.f;
    if (tid < 8) {
        float z0 = zt0[base8 + tid], g0 = ht0[base8 + tid], p0 = hp0[base8 + tid];
        p_cur = (1.0f - z0) * p0 + z0 * g0;
        unsigned long long pr = (1ull << 32) | (unsigned long long)__float_as_uint(p_cur);
        __hip_atomic_store(&Hbuf[(size_t)1 * NHH + base8 + tid], pr,
                           __ATOMIC_RELAXED, __HIP_MEMORY_SCOPE_SYSTEM);
    }
    __syncthreads();

    for (int t = 1; t < TT; ++t) {
        // (i) issue loads for epoch t; results not touched until (iv)
        const unsigned long long* __restrict__ src = Hbuf + (size_t)(t & 3) * NHH;
        unsigned long long pv[8];
#pragma unroll
        for (int k = 0; k < 8; ++k)
            pv[k] = __hip_atomic_load(&src[k * 256 + tid], __ATOMIC_RELAXED, __HIP_MEMORY_SCOPE_SYSTEM);
        float xzv = 0.f, xhv = 0.f;
        if (tid < 8) {
            xzv = XZ[(size_t)(t - 1) * NHH + base8 + tid];
            xhv = XH[(size_t)(t - 1) * NHH + base8 + tid];
        }
        // (ii) matvec: U @ P_{t-1} from LDS, 4 rows/wave, U in registers
        float a0 = 0.f, a1 = 0.f, a2 = 0.f, a3 = 0.f;
#pragma unroll
        for (int c = 0; c < 8; ++c) {
            float4 h4 = *(const float4*)&Hs[c * 256 + lane * 4];
            a0 = fmaf(u[0][c*4+0], h4.x, fmaf(u[0][c*4+1], h4.y, fmaf(u[0][c*4+2], h4.z, fmaf(u[0][c*4+3], h4.w, a0))));
            a1 = fmaf(u[1][c*4+0], h4.x, fmaf(u[1][c*4+1], h4.y, fmaf(u[1][c*4+2], h4.z, fmaf(u[1][c*4+3], h4.w, a1))));
            a2 = fmaf(u[2][c*4+0], h4.x, fmaf(u[2][c*4+1], h4.y, fmaf(u[2][c*4+2], h4.z, fmaf(u[2][c*4+3], h4.w, a2))));
            a3 = fmaf(u[3][c*4+0], h4.x, fmaf(u[3][c*4+1], h4.y, fmaf(u[3][c*4+2], h4.z, fmaf(u[3][c*4+3], h4.w, a3))));
        }
#pragma unroll
        for (int off = 32; off > 0; off >>= 1) {
            a0 += __shfl_xor(a0, off);
            a1 += __shfl_xor(a1, off);
            a2 += __shfl_xor(a2, off);
            a3 += __shfl_xor(a3, off);
        }
        if (lane == 0) {
            int di = ((wave & 1) * 4) + ((wave >> 1) * 8); // Uz -> 0..7, Uh -> 8..15
            dot_s[di + 0] = a0; dot_s[di + 1] = a1; dot_s[di + 2] = a2; dot_s[di + 3] = a3;
        }
        __syncthreads();
        // (iii) gates from P_{t-1} dots; P_{t+1} = (1-z)*P_t + z*g; publish
        if (tid < 8) {
            float z = 1.0f / (1.0f + expf(-(xzv + dot_s[tid])));
            float g = tanhf(xhv + dot_s[8 + tid]);
            float pn = (1.0f - z) * p_cur + z * g;
            p_cur = pn;
            unsigned long long pr = ((unsigned long long)(unsigned)(t + 1) << 32)
                                  | (unsigned long long)__float_as_uint(pn);
            __hip_atomic_store(&Hbuf[(size_t)((t + 1) & 3) * NHH + base8 + tid], pr,
                               __ATOMIC_RELAXED, __HIP_MEMORY_SCOPE_SYSTEM);
        }
        // (iv) validate epoch-t tags; batched parallel retry of stale ones
        for (;;) {
            unsigned stale = 0;
#pragma unroll
            for (int k = 0; k < 8; ++k)
                if ((unsigned)(pv[k] >> 32) != (unsigned)t) stale |= (1u << k);
            if (!stale) break;
#pragma unroll
            for (int k = 0; k < 8; ++k)
                if (stale & (1u << k))
                    pv[k] = __hip_atomic_load(&src[k * 256 + tid], __ATOMIC_RELAXED, __HIP_MEMORY_SCOPE_SYSTEM);
        }
#pragma unroll
        for (int k = 0; k < 8; ++k) Hs[k * 256 + tid] = __uint_as_float((unsigned)pv[k]);
        __syncthreads();
    }
}

// ---------------------------------------------------------------------------
// logits[r] = Wout[r,:] . P_1024   (epoch 1024 -> slot 0, value in low bits)
// ---------------------------------------------------------------------------
__global__ __launch_bounds__(256) void k_logits(const unsigned long long* __restrict__ Hbuf,
                                                const float* __restrict__ Wout,
                                                float* __restrict__ lg) {
    __shared__ float Hs[NHH];
    const int tid = threadIdx.x;
    for (int k = tid; k < NHH; k += 256) Hs[k] = __uint_as_float((unsigned)Hbuf[k]);
    __syncthreads();
    const int wave = tid >> 6, lane = tid & 63;
    const int row = blockIdx.x * 4 + wave;
    float a = 0.f;
#pragma unroll
    for (int c = 0; c < 8; ++c) {
        float4 w = *(const float4*)&Wout[(size_t)row * NHH + c * 256 + lane * 4];
        float4 h = *(const float4*)&Hs[c * 256 + lane * 4];
        a = fmaf(w.x, h.x, fmaf(w.y, h.y, fmaf(w.z, h.z, fmaf(w.w, h.w, a))));
    }
#pragma unroll
    for (int off = 32; off > 0; off >>= 1) a += __shfl_xor(a, off);
    if (lane == 0) lg[row] = a;
}

// ---------------------------------------------------------------------------
// softmax over 1000 logits, single block
// ---------------------------------------------------------------------------
__global__ __launch_bounds__(1024) void k_softmax(const float* __restrict__ lg,
                                                  float* __restrict__ out) {
    const int i = threadIdx.x;
    __shared__ float red[16];
    __shared__ float bc[2];
    float v = (i < CC) ? lg[i] : -3.0e38f;
    float m = v;
#pragma unroll
    for (int off = 32; off > 0; off >>= 1) m = fmaxf(m, __shfl_xor(m, off));
    if ((i & 63) == 0) red[i >> 6] = m;
    __syncthreads();
    if (i == 0) { float mm = red[0]; for (int k = 1; k < 16; ++k) mm = fmaxf(mm, red[k]); bc[0] = mm; }
    __syncthreads();
    float e = (i < CC) ? expf(v - bc[0]) : 0.f;
    float s = e;
#pragma unroll
    for (int off = 32; off > 0; off >>= 1) s += __shfl_xor(s, off);
    if ((i & 63) == 0) red[i >> 6] = s;
    __syncthreads();
    if (i == 0) { float ss = 0.f; for (int k = 0; k < 16; ++k) ss += red[k]; bc[1] = ss; }
    __syncthreads();
    if (i < CC) out[i] = e / bc[1];
}

extern "C" void kernel_launch(void* const* d_in, const int* in_sizes, int n_in,
                              void* d_out, int out_size, void* d_ws, size_t ws_size,
                              hipStream_t stream) {
    const float* x    = (const float*)d_in[0];
    const float* Wh   = (const float*)d_in[1];
    const float* Wz   = (const float*)d_in[2];
    // d_in[3] = Wr  (dead code in reference)
    const float* Uh   = (const float*)d_in[4];
    const float* Uz   = (const float*)d_in[5];
    const float* bz   = (const float*)d_in[6];
    // d_in[7] = Ur, d_in[8] = br (dead code)
    const float* Wout = (const float*)d_in[9];
    // d_in[10] = h0 (overwritten before first use since T>=1)
    const float* zt0  = (const float*)d_in[11];
    const float* ht0  = (const float*)d_in[12];
    const float* hp0  = (const float*)d_in[13];
    float* out = (float*)d_out;

    float* XH = (float*)d_ws;                                   // T*NH f32
    float* XZ = XH + (size_t)TT * NHH;                          // T*NH f32
    unsigned long long* Hbuf = (unsigned long long*)(XZ + (size_t)TT * NHH); // 4*NH u64
    float* lg = (float*)(Hbuf + 4 * NHH);                       // CC f32

    k_gemm<<<dim3(NHH / 128, TT / 128, 2), dim3(256), 0, stream>>>(x, Wh, Wz, bz, XH, XZ);
    k_recur<<<dim3(256), dim3(256), 0, stream>>>(XH, XZ, Uh, Uz, zt0, ht0, hp0, Hbuf);
    k_logits<<<dim3(250), dim3(256), 0, stream>>>(Hbuf, Wout, lg);
    k_softmax<<<dim3(1), dim3(1024), 0, stream>>>(lg, out);
}